// Round 6
// baseline (476.415 us; speedup 1.0000x reference)
//
#include <hip/hip_runtime.h>
#include <hip/hip_cooperative_groups.h>

namespace cg = cooperative_groups;

typedef unsigned short u16;
typedef __attribute__((ext_vector_type(8))) short short8;
typedef __attribute__((ext_vector_type(4))) float floatx4;

#define NB 8
#define NN 1024
#define KDIM 256
#define ODIM 256
#define NH 8
#define LDA 264      // padded LDS row stride (shorts): 2-way (free) bank aliasing
#define ECAP 256     // neighbor capacity (nnz mean ~52, sigma ~7)
#define ESTR 260     // esc row stride (floats): heads land on distinct banks

__device__ __forceinline__ u16 bf_rne(float x) {
    union { float f; unsigned u; } c{x};
    unsigned r = c.u + 0x7fff + ((c.u >> 16) & 1);  // RNE to bf16
    return (u16)(r >> 16);
}
__device__ __forceinline__ float bf_f(u16 b) {
    union { unsigned u; float f; } c{(unsigned)b << 16};
    return c.f;
}
#define SPLIT1(val, A_, B_) { u16 hh_ = bf_rne(val); u16 ll_ = bf_rne((val) - bf_f(hh_)); A_ = hh_; B_ = ll_; }

// ======================= fused cooperative kernel =======================
// grid 1024 x 256. Phase 0: W split-transpose (blocks 0..15) overlapped with
// per-block X->LDS bf16 hi/lo staging. Phase 1: split-bf16 MFMA GEMM, wave =
// one head (32 cols), in-wave score reduction. Phase 2: 8 rows/block sparse
// softmax + float4 gather.
__global__ __launch_bounds__(256, 4) void gat_fused(
        const float* __restrict__ A, const float* __restrict__ X,
        const float* __restrict__ W, const float* __restrict__ fc1,
        const float* __restrict__ fc2, float* __restrict__ inp,
        u16* __restrict__ WhiT, u16* __restrict__ WloT,
        float* __restrict__ self_s, float* __restrict__ neigh_s,
        float* __restrict__ out) {
    __shared__ __align__(16) char smem[17408];
    u16* ah_lds = (u16*)smem;
    u16* al_lds = ah_lds + 16 * LDA;

    int tid = threadIdx.x;
    int bid = blockIdx.x;
    int w = tid >> 6, lane = tid & 63;
    int m = lane & 15, q = lane >> 4;

    cg::grid_group grid = cg::this_grid();

    // ---- phase 0a: W prep (blocks 0..15), LDS-transposed, coalesced ----
    if (bid < 16) {
        float (*wtile)[65] = (float(*)[65])smem;
        int kt = bid >> 2, ot = bid & 3;
        int r = tid >> 6, c = tid & 63;
#pragma unroll
        for (int rr = r; rr < 64; rr += 4)
            wtile[rr][c] = W[(kt * 64 + rr) * ODIM + ot * 64 + c];
        __syncthreads();
#pragma unroll
        for (int oo = r; oo < 64; oo += 4) {
            float wv = wtile[c][oo];
            u16 h, l;
            SPLIT1(wv, h, l)
            WhiT[(ot * 64 + oo) * KDIM + kt * 64 + c] = h;
            WloT[(ot * 64 + oo) * KDIM + kt * 64 + c] = l;
        }
        __syncthreads();    // done with wtile before X staging reuses smem
    }

    // ---- phase 0b: stage this block's 16 X rows -> hi/lo bf16 LDS ----
    int rb = bid >> 1;
    int row0 = rb * 16;
    int cbase = (bid & 1) * 128;
    {
        const float4* Xr = (const float4*)(X + (size_t)row0 * KDIM);
#pragma unroll
        for (int p = 0; p < 4; ++p) {
            int f = p * 256 + tid;
            int r = f >> 6, c4 = (f & 63) * 4;
            float4 v = Xr[f];
            ushort4 hi, lo;
            SPLIT1(v.x, hi.x, lo.x)
            SPLIT1(v.y, hi.y, lo.y)
            SPLIT1(v.z, hi.z, lo.z)
            SPLIT1(v.w, hi.w, lo.w)
            *(ushort4*)&ah_lds[r * LDA + c4] = hi;
            *(ushort4*)&al_lds[r * LDA + c4] = lo;
        }
    }
    if (bid < 16) __threadfence();   // publish WhiT/WloT across XCDs
    grid.sync();

    // ---- phase 1: GEMM (3-product split-bf16) + per-head score reduction ----
    floatx4 acc[2] = {{0, 0, 0, 0}, {0, 0, 0, 0}};
#pragma unroll
    for (int k0 = 0; k0 < KDIM; k0 += 32) {
        short8 Ah = *(const short8*)&ah_lds[m * LDA + k0 + q * 8];
        short8 Al = *(const short8*)&al_lds[m * LDA + k0 + q * 8];
#pragma unroll
        for (int t = 0; t < 2; ++t) {
            int o = cbase + w * 32 + t * 16 + m;
            short8 Bh = *(const short8*)(WhiT + (size_t)o * KDIM + k0 + q * 8);
            short8 Bl = *(const short8*)(WloT + (size_t)o * KDIM + k0 + q * 8);
            acc[t] = __builtin_amdgcn_mfma_f32_16x16x32_bf16(Ah, Bh, acc[t], 0, 0, 0);
            acc[t] = __builtin_amdgcn_mfma_f32_16x16x32_bf16(Ah, Bl, acc[t], 0, 0, 0);
            acc[t] = __builtin_amdgcn_mfma_f32_16x16x32_bf16(Al, Bh, acc[t], 0, 0, 0);
        }
    }
#pragma unroll
    for (int t = 0; t < 2; ++t) {
        int col = cbase + w * 32 + t * 16 + m;
#pragma unroll
        for (int r = 0; r < 4; ++r)
            inp[(size_t)(row0 + q * 4 + r) * ODIM + col] = acc[t][r];
    }
    {
        int hd = (bid & 1) * 4 + w;              // wave's head
        float f1[2], f2[2];
#pragma unroll
        for (int t = 0; t < 2; ++t) {
            int col = hd * 32 + t * 16 + m;
            f1[t] = fc1[col];
            f2[t] = fc2[col];
        }
#pragma unroll
        for (int r = 0; r < 4; ++r) {
            float a = acc[0][r] * f1[0] + acc[1][r] * f1[1];
            float bb = acc[0][r] * f2[0] + acc[1][r] * f2[1];
#pragma unroll
            for (int ofs = 8; ofs >= 1; ofs >>= 1) {
                a += __shfl_xor(a, ofs);
                bb += __shfl_xor(bb, ofs);
            }
            if (m == 0) {
                int n = row0 + q * 4 + r;
                int b = n >> 10, nn = n & 1023;
                self_s [((size_t)(b * NH + hd) << 10) + nn] = a;
                neigh_s[((size_t)(b * NH + hd) << 10) + nn] = bb;
            }
        }
    }
    __threadfence();   // publish inp/self_s/neigh_s across XCDs
    grid.sync();

    // ---- phase 2: 8 rows/block sparse softmax + gather ----
    u16*  lst  = (u16*)smem;                       // 2048 B
    float* esc = (float*)(smem + 2048);            // 8*260*4 = 8320 B
    float* red = (float*)(smem + 10368);           // 4096 B (16B aligned)
    float* hinv = (float*)(smem + 14464);          // 32 B
    int*  cntp = (int*)(smem + 14496);

    int b2 = bid >> 7;                             // 8 rows all in batch b2
    int h = tid >> 5, j = tid & 31;
    int hh = lane >> 3;
    const float4* ib = (const float4*)(inp + ((size_t)b2 << 10) * ODIM) + lane;

    for (int rr = 0; rr < 8; ++rr) {
        int bn = bid * 8 + rr;
        int n = bn & 1023;

        if (tid == 0) *cntp = 0;
        __syncthreads();
        {
            float4 a4 = ((const float4*)(A + (size_t)bn * NN))[tid];
            int base = tid * 4;
            if (a4.x != 0.f) lst[atomicAdd(cntp, 1)] = (u16)base;
            if (a4.y != 0.f) lst[atomicAdd(cntp, 1)] = (u16)(base + 1);
            if (a4.z != 0.f) lst[atomicAdd(cntp, 1)] = (u16)(base + 2);
            if (a4.w != 0.f) lst[atomicAdd(cntp, 1)] = (u16)(base + 3);
        }
        __syncthreads();
        int nnz = *cntp;
        if (nnz > ECAP) nnz = ECAP;

        // fused exp + sum per head (scores bounded; no max pass)
        const float* nsh = neigh_s + ((size_t)(b2 * NH + h) << 10);
        float selfv = self_s[((size_t)(b2 * NH + h) << 10) + n];
        float lsum = 0.f;
        for (int i = j; i < nnz; i += 32) {
            float s = selfv + nsh[lst[i]];
            s = s > 0.f ? s : 0.01f * s;
            float e = __expf(s);
            esc[h * ESTR + i] = e;
            lsum += e;
        }
#pragma unroll
        for (int ofs = 16; ofs >= 1; ofs >>= 1)
            lsum += __shfl_xor(lsum, ofs);
        if (j == 0) hinv[h] = 1.f / lsum;
        __syncthreads();

        // gather: wave w takes i = w, w+4, ...; wave reads one 1KB inp row
        floatx4 acc2 = {0.f, 0.f, 0.f, 0.f};
#pragma unroll 4
        for (int i = w; i < nnz; i += 4) {
            float e = esc[hh * ESTR + i];
            float4 v = ib[(size_t)lst[i] * 64];
            acc2[0] = fmaf(e, v.x, acc2[0]);
            acc2[1] = fmaf(e, v.y, acc2[1]);
            acc2[2] = fmaf(e, v.z, acc2[2]);
            acc2[3] = fmaf(e, v.w, acc2[3]);
        }
        *(floatx4*)&red[w * 256 + lane * 4] = acc2;
        __syncthreads();

        float r0 = red[tid] + red[256 + tid] + red[512 + tid] + red[768 + tid];
        r0 *= hinv[tid >> 5];
        out[(size_t)bn * ODIM + tid] = r0 > 0.f ? r0 : 0.f;
        __syncthreads();   // protect lst/esc/red before next row
    }
}

// ======================= fallback (round-5 proven path) =======================
__global__ __launch_bounds__(256) void wprep(const float* __restrict__ W,
                                             u16* __restrict__ WhiT,
                                             u16* __restrict__ WloT) {
    __shared__ float tile[64][65];
    int bt = blockIdx.x;
    int kt = bt >> 2, ot = bt & 3;
    int tid = threadIdx.x;
    int r = tid >> 6, c = tid & 63;
#pragma unroll
    for (int rr = r; rr < 64; rr += 4)
        tile[rr][c] = W[(kt * 64 + rr) * ODIM + ot * 64 + c];
    __syncthreads();
#pragma unroll
    for (int oo = r; oo < 64; oo += 4) {
        float w = tile[c][oo];
        u16 h, l;
        SPLIT1(w, h, l)
        WhiT[(ot * 64 + oo) * KDIM + kt * 64 + c] = h;
        WloT[(ot * 64 + oo) * KDIM + kt * 64 + c] = l;
    }
}

__global__ __launch_bounds__(256) void gemm_scores(
        const float* __restrict__ X, const u16* __restrict__ WhiT,
        const u16* __restrict__ WloT, const float* __restrict__ fc1,
        const float* __restrict__ fc2, float* __restrict__ inp,
        float* __restrict__ self_s, float* __restrict__ neigh_s) {
    __shared__ u16 ah_lds[16 * LDA];
    __shared__ u16 al_lds[16 * LDA];

    int tid = threadIdx.x;
    int w = tid >> 6, lane = tid & 63;
    int m = lane & 15, q = lane >> 4;
    int row0 = blockIdx.x * 16;

    const float4* Xr = (const float4*)(X + (size_t)row0 * KDIM);
#pragma unroll
    for (int p = 0; p < 4; ++p) {
        int f = p * 256 + tid;
        int r = f >> 6, c4 = (f & 63) * 4;
        float4 v = Xr[f];
        ushort4 hi, lo;
        SPLIT1(v.x, hi.x, lo.x)
        SPLIT1(v.y, hi.y, lo.y)
        SPLIT1(v.z, hi.z, lo.z)
        SPLIT1(v.w, hi.w, lo.w)
        *(ushort4*)&ah_lds[r * LDA + c4] = hi;
        *(ushort4*)&al_lds[r * LDA + c4] = lo;
    }
    __syncthreads();

    floatx4 acc[4] = {{0,0,0,0},{0,0,0,0},{0,0,0,0},{0,0,0,0}};
#pragma unroll
    for (int k0 = 0; k0 < KDIM; k0 += 32) {
        short8 Ah = *(const short8*)&ah_lds[m * LDA + k0 + q * 8];
        short8 Al = *(const short8*)&al_lds[m * LDA + k0 + q * 8];
#pragma unroll
        for (int t = 0; t < 4; ++t) {
            int o = w * 64 + t * 16 + m;
            short8 Bh = *(const short8*)(WhiT + (size_t)o * KDIM + k0 + q * 8);
            short8 Bl = *(const short8*)(WloT + (size_t)o * KDIM + k0 + q * 8);
            acc[t] = __builtin_amdgcn_mfma_f32_16x16x32_bf16(Ah, Bh, acc[t], 0, 0, 0);
            acc[t] = __builtin_amdgcn_mfma_f32_16x16x32_bf16(Ah, Bl, acc[t], 0, 0, 0);
            acc[t] = __builtin_amdgcn_mfma_f32_16x16x32_bf16(Al, Bh, acc[t], 0, 0, 0);
        }
    }

#pragma unroll
    for (int t = 0; t < 4; ++t) {
        int col = w * 64 + t * 16 + m;
#pragma unroll
        for (int r = 0; r < 4; ++r)
            inp[(size_t)(row0 + q * 4 + r) * ODIM + col] = acc[t][r];
    }

    float f1[4], f2[4];
#pragma unroll
    for (int t = 0; t < 4; ++t) {
        int col = w * 64 + t * 16 + m;
        f1[t] = fc1[col];
        f2[t] = fc2[col];
    }
#pragma unroll
    for (int r = 0; r < 4; ++r) {
        float a0 = acc[0][r] * f1[0] + acc[1][r] * f1[1];
        float b0 = acc[0][r] * f2[0] + acc[1][r] * f2[1];
        float a1 = acc[2][r] * f1[2] + acc[3][r] * f1[3];
        float b1 = acc[2][r] * f2[2] + acc[3][r] * f2[3];
#pragma unroll
        for (int ofs = 8; ofs >= 1; ofs >>= 1) {
            a0 += __shfl_xor(a0, ofs);
            b0 += __shfl_xor(b0, ofs);
            a1 += __shfl_xor(a1, ofs);
            b1 += __shfl_xor(b1, ofs);
        }
        if (m == 0) {
            int n = row0 + q * 4 + r;
            int b = n >> 10, nn = n & 1023;
            self_s [((size_t)(b * NH + 2 * w) << 10) + nn] = a0;
            neigh_s[((size_t)(b * NH + 2 * w) << 10) + nn] = b0;
            self_s [((size_t)(b * NH + 2 * w + 1) << 10) + nn] = a1;
            neigh_s[((size_t)(b * NH + 2 * w + 1) << 10) + nn] = b1;
        }
    }
}

__global__ __launch_bounds__(256) void gat_agg(
        const float* __restrict__ A, const float* __restrict__ inp,
        const float* __restrict__ self_s, const float* __restrict__ neigh_s,
        float* __restrict__ out) {
    __shared__ u16 lst[NN];
    __shared__ float esc[NH][ESTR];
    __shared__ float red[4][256];
    __shared__ float hinv[NH];
    __shared__ int cnt;

    int bx = blockIdx.x;
    int b = bx & 7;
    int n = bx >> 3;
    int bn = (b << 10) | n;
    int tid = threadIdx.x;

    if (tid == 0) cnt = 0;
    __syncthreads();
    {
        float4 a4 = ((const float4*)(A + (size_t)bn * NN))[tid];
        int base = tid * 4;
        if (a4.x != 0.f) lst[atomicAdd(&cnt, 1)] = (u16)base;
        if (a4.y != 0.f) lst[atomicAdd(&cnt, 1)] = (u16)(base + 1);
        if (a4.z != 0.f) lst[atomicAdd(&cnt, 1)] = (u16)(base + 2);
        if (a4.w != 0.f) lst[atomicAdd(&cnt, 1)] = (u16)(base + 3);
    }
    __syncthreads();
    int nnz = cnt;
    if (nnz > ECAP) nnz = ECAP;

    int h = tid >> 5, j = tid & 31;
    const float* nsh = neigh_s + ((size_t)(b * NH + h) << 10);
    float selfv = self_s[((size_t)(b * NH + h) << 10) + n];
    float lsum = 0.f;
    for (int i = j; i < nnz; i += 32) {
        float s = selfv + nsh[lst[i]];
        s = s > 0.f ? s : 0.01f * s;
        float e = __expf(s);
        esc[h][i] = e;
        lsum += e;
    }
#pragma unroll
    for (int ofs = 16; ofs >= 1; ofs >>= 1)
        lsum += __shfl_xor(lsum, ofs);
    if (j == 0) hinv[h] = 1.f / lsum;
    __syncthreads();

    int wv = tid >> 6, lane = tid & 63;
    int hh = lane >> 3;
    const float4* ib = (const float4*)(inp + ((size_t)b << 10) * ODIM) + lane;
    floatx4 acc = {0.f, 0.f, 0.f, 0.f};
#pragma unroll 2
    for (int i = wv; i < nnz; i += 4) {
        float e = esc[hh][i];
        float4 v = ib[(size_t)lst[i] * 64];
        acc[0] = fmaf(e, v.x, acc[0]);
        acc[1] = fmaf(e, v.y, acc[1]);
        acc[2] = fmaf(e, v.z, acc[2]);
        acc[3] = fmaf(e, v.w, acc[3]);
    }
    *(floatx4*)&red[wv][lane * 4] = acc;
    __syncthreads();

    float r0 = red[0][tid] + red[1][tid] + red[2][tid] + red[3][tid];
    r0 *= hinv[tid >> 5];
    out[(size_t)bn * ODIM + tid] = r0 > 0.f ? r0 : 0.f;
}

extern "C" void kernel_launch(void* const* d_in, const int* in_sizes, int n_in,
                              void* d_out, int out_size, void* d_ws, size_t ws_size,
                              hipStream_t stream) {
    const float* A   = (const float*)d_in[0];   // [B,N,N]
    const float* X   = (const float*)d_in[1];   // [B,N,256]
    const float* W   = (const float*)d_in[2];   // [256,256]
    const float* fc1 = (const float*)d_in[3];   // [H,D] flat 256
    const float* fc2 = (const float*)d_in[4];   // [H,D] flat 256
    float* out = (float*)d_out;                 // [B,N,256]

    char* ws = (char*)d_ws;
    const size_t MB = 1024u * 1024u;
    float* inp     = (float*)ws;                          // 8 MB
    u16*   WhiT    = (u16*)(ws + 8 * MB);                 // 128 KB
    u16*   WloT    = (u16*)(ws + 8 * MB + 128 * 1024);    // 128 KB
    float* self_s  = (float*)(ws + 8 * MB + 256 * 1024);  // 256 KB
    float* neigh_s = (float*)(ws + 8 * MB + 512 * 1024);  // 256 KB

    void* args[] = {(void*)&A, (void*)&X, (void*)&W, (void*)&fc1, (void*)&fc2,
                    (void*)&inp, (void*)&WhiT, (void*)&WloT, (void*)&self_s,
                    (void*)&neigh_s, (void*)&out};
    hipError_t e = hipLaunchCooperativeKernel((const void*)gat_fused,
                                              dim3(1024), dim3(256),
                                              args, 0, stream);
    if (e != hipSuccess) {
        // fallback: proven 3-kernel path (round-5 behavior)
        wprep<<<16, 256, 0, stream>>>(W, WhiT, WloT);
        gemm_scores<<<NB * NN / 16, 256, 0, stream>>>(
            X, WhiT, WloT, fc1, fc2, inp, self_s, neigh_s);
        gat_agg<<<NB * NN, 256, 0, stream>>>(A, inp, self_s, neigh_s, out);
    }
}

// Round 7
// 136.747 us; speedup vs baseline: 3.4839x; 3.4839x over previous
//
#include <hip/hip_runtime.h>

typedef unsigned short u16;
typedef __attribute__((ext_vector_type(8))) short short8;
typedef __attribute__((ext_vector_type(4))) float floatx4;

#define NB 8
#define NN 1024
#define KDIM 256
#define ODIM 256
#define NH 8
#define LDA 264      // padded LDS row stride (shorts): 2-way (free) bank aliasing
#define ECAP 256     // neighbor capacity (nnz mean ~52, sigma ~7)
#define ESTR 260     // esc row stride (floats): heads land on distinct banks

__device__ __forceinline__ u16 bf_rne(float x) {
    union { float f; unsigned u; } c{x};
    unsigned r = c.u + 0x7fff + ((c.u >> 16) & 1);  // RNE to bf16
    return (u16)(r >> 16);
}
__device__ __forceinline__ float bf_f(u16 b) {
    union { unsigned u; float f; } c{(unsigned)b << 16};
    return c.f;
}
#define SPLIT1(val, A_, B_) { u16 hh_ = bf_rne(val); u16 ll_ = bf_rne((val) - bf_f(hh_)); A_ = hh_; B_ = ll_; }

// ---- k0: W [256,256] -> WhiT/WloT [O][K] bf16 split-transpose, coalesced ----
__global__ __launch_bounds__(256) void wprep(const float* __restrict__ W,
                                             u16* __restrict__ WhiT,
                                             u16* __restrict__ WloT) {
    __shared__ float tile[64][65];
    int bt = blockIdx.x;              // 0..15
    int kt = bt >> 2, ot = bt & 3;
    int tid = threadIdx.x;
    int r = tid >> 6, c = tid & 63;
#pragma unroll
    for (int rr = r; rr < 64; rr += 4)
        tile[rr][c] = W[(kt * 64 + rr) * ODIM + ot * 64 + c];
    __syncthreads();
#pragma unroll
    for (int oo = r; oo < 64; oo += 4) {
        float w = tile[c][oo];
        u16 h, l;
        SPLIT1(w, h, l)
        WhiT[(ot * 64 + oo) * KDIM + kt * 64 + c] = h;
        WloT[(ot * 64 + oo) * KDIM + kt * 64 + c] = l;
    }
}

// ---- k1: fused X-split + MFMA GEMM (3-product split-bf16) + score reductions ----
__global__ __launch_bounds__(256) void gemm_scores(
        const float* __restrict__ X, const u16* __restrict__ WhiT,
        const u16* __restrict__ WloT, const float* __restrict__ fc1,
        const float* __restrict__ fc2, float* __restrict__ inp,
        float* __restrict__ self_s, float* __restrict__ neigh_s) {
    __shared__ u16 ah_lds[16 * LDA];
    __shared__ u16 al_lds[16 * LDA];

    int tid = threadIdx.x;
    int w = tid >> 6, lane = tid & 63;
    int m = lane & 15, q = lane >> 4;
    int row0 = blockIdx.x * 16;

    // stage 16 X rows -> hi/lo bf16 LDS; X is read-once -> nontemporal
    const floatx4* Xr = (const floatx4*)(X + (size_t)row0 * KDIM);
#pragma unroll
    for (int p = 0; p < 4; ++p) {
        int f = p * 256 + tid;
        int r = f >> 6, c4 = (f & 63) * 4;
        floatx4 v = __builtin_nontemporal_load(Xr + f);
        ushort4 hi, lo;
        SPLIT1(v[0], hi.x, lo.x)
        SPLIT1(v[1], hi.y, lo.y)
        SPLIT1(v[2], hi.z, lo.z)
        SPLIT1(v[3], hi.w, lo.w)
        *(ushort4*)&ah_lds[r * LDA + c4] = hi;
        *(ushort4*)&al_lds[r * LDA + c4] = lo;
    }
    __syncthreads();

    floatx4 acc[4] = {{0,0,0,0},{0,0,0,0},{0,0,0,0},{0,0,0,0}};
#pragma unroll
    for (int k0 = 0; k0 < KDIM; k0 += 32) {
        short8 Ah = *(const short8*)&ah_lds[m * LDA + k0 + q * 8];
        short8 Al = *(const short8*)&al_lds[m * LDA + k0 + q * 8];
#pragma unroll
        for (int t = 0; t < 4; ++t) {
            int o = w * 64 + t * 16 + m;
            short8 Bh = *(const short8*)(WhiT + (size_t)o * KDIM + k0 + q * 8);
            short8 Bl = *(const short8*)(WloT + (size_t)o * KDIM + k0 + q * 8);
            acc[t] = __builtin_amdgcn_mfma_f32_16x16x32_bf16(Ah, Bh, acc[t], 0, 0, 0);
            acc[t] = __builtin_amdgcn_mfma_f32_16x16x32_bf16(Ah, Bl, acc[t], 0, 0, 0);
            acc[t] = __builtin_amdgcn_mfma_f32_16x16x32_bf16(Al, Bh, acc[t], 0, 0, 0);
        }
    }

#pragma unroll
    for (int t = 0; t < 4; ++t) {
        int col = w * 64 + t * 16 + m;
#pragma unroll
        for (int r = 0; r < 4; ++r)
            inp[(size_t)(row0 + q * 4 + r) * ODIM + col] = acc[t][r];
    }

    float f1[4], f2[4];
#pragma unroll
    for (int t = 0; t < 4; ++t) {
        int col = w * 64 + t * 16 + m;
        f1[t] = fc1[col];
        f2[t] = fc2[col];
    }
#pragma unroll
    for (int r = 0; r < 4; ++r) {
        float a0 = acc[0][r] * f1[0] + acc[1][r] * f1[1];
        float b0 = acc[0][r] * f2[0] + acc[1][r] * f2[1];
        float a1 = acc[2][r] * f1[2] + acc[3][r] * f1[3];
        float b1 = acc[2][r] * f2[2] + acc[3][r] * f2[3];
#pragma unroll
        for (int ofs = 8; ofs >= 1; ofs >>= 1) {
            a0 += __shfl_xor(a0, ofs);
            b0 += __shfl_xor(b0, ofs);
            a1 += __shfl_xor(a1, ofs);
            b1 += __shfl_xor(b1, ofs);
        }
        if (m == 0) {
            int n = row0 + q * 4 + r;
            int b = n >> 10, nn = n & 1023;
            self_s [((size_t)(b * NH + 2 * w) << 10) + nn] = a0;
            neigh_s[((size_t)(b * NH + 2 * w) << 10) + nn] = b0;
            self_s [((size_t)(b * NH + 2 * w + 1) << 10) + nn] = a1;
            neigh_s[((size_t)(b * NH + 2 * w + 1) << 10) + nn] = b1;
        }
    }
}

// ---- k2: sparse softmax + vectorized gather ----
// A is streamed once -> nontemporal loads; out written once -> nontemporal
// stores. Keeps inp (8 MB) + score arrays resident in L2 for the gather.
__global__ __launch_bounds__(256) void gat_agg(
        const float* __restrict__ A, const float* __restrict__ inp,
        const float* __restrict__ self_s, const float* __restrict__ neigh_s,
        float* __restrict__ out) {
    __shared__ u16 lst[NN];
    __shared__ float esc[NH][ESTR];
    __shared__ float red[4][256];
    __shared__ float hinv[NH];
    __shared__ int cnt;

    int bx = blockIdx.x;
    int b = bx & 7;              // XCD-aligned batch
    int n = bx >> 3;
    int bn = (b << 10) | n;
    int tid = threadIdx.x;

    if (tid == 0) cnt = 0;
    __syncthreads();
    {
        floatx4 a4 = __builtin_nontemporal_load(
            (const floatx4*)(A + (size_t)bn * NN) + tid);
        int base = tid * 4;
        if (a4[0] != 0.f) lst[atomicAdd(&cnt, 1)] = (u16)base;
        if (a4[1] != 0.f) lst[atomicAdd(&cnt, 1)] = (u16)(base + 1);
        if (a4[2] != 0.f) lst[atomicAdd(&cnt, 1)] = (u16)(base + 2);
        if (a4[3] != 0.f) lst[atomicAdd(&cnt, 1)] = (u16)(base + 3);
    }
    __syncthreads();
    int nnz = cnt;
    if (nnz > ECAP) nnz = ECAP;

    // fused exp+sum per head (scores bounded; no max pass needed)
    int h = tid >> 5, j = tid & 31;
    const float* nsh = neigh_s + ((size_t)(b * NH + h) << 10);
    float selfv = self_s[((size_t)(b * NH + h) << 10) + n];
    float lsum = 0.f;
    for (int i = j; i < nnz; i += 32) {
        float s = selfv + nsh[lst[i]];
        s = s > 0.f ? s : 0.01f * s;
        float e = __expf(s);
        esc[h][i] = e;
        lsum += e;
    }
#pragma unroll
    for (int ofs = 16; ofs >= 1; ofs >>= 1)
        lsum += __shfl_xor(lsum, ofs);
    if (j == 0) hinv[h] = 1.f / lsum;
    __syncthreads();

    // gather: wave wv takes i = wv, wv+4, ...; wave reads one full 1KB inp row
    int wv = tid >> 6, lane = tid & 63;
    int hh = lane >> 3;
    const floatx4* ib = (const floatx4*)(inp + ((size_t)b << 10) * ODIM) + lane;
    floatx4 acc = {0.f, 0.f, 0.f, 0.f};
#pragma unroll 4
    for (int i = wv; i < nnz; i += 4) {
        float e = esc[hh][i];
        floatx4 v = ib[(size_t)lst[i] * 64];
        acc[0] = fmaf(e, v[0], acc[0]);
        acc[1] = fmaf(e, v[1], acc[1]);
        acc[2] = fmaf(e, v[2], acc[2]);
        acc[3] = fmaf(e, v[3], acc[3]);
    }
    *(floatx4*)&red[wv][lane * 4] = acc;
    __syncthreads();

    float r0 = red[0][tid] + red[1][tid] + red[2][tid] + red[3][tid];
    r0 *= hinv[tid >> 5];
    r0 = r0 > 0.f ? r0 : 0.f;
    __builtin_nontemporal_store(r0, out + (size_t)bn * ODIM + tid);
}

extern "C" void kernel_launch(void* const* d_in, const int* in_sizes, int n_in,
                              void* d_out, int out_size, void* d_ws, size_t ws_size,
                              hipStream_t stream) {
    const float* A   = (const float*)d_in[0];   // [B,N,N]
    const float* X   = (const float*)d_in[1];   // [B,N,256]
    const float* W   = (const float*)d_in[2];   // [256,256]
    const float* fc1 = (const float*)d_in[3];   // [H,D] flat 256
    const float* fc2 = (const float*)d_in[4];   // [H,D] flat 256
    float* out = (float*)d_out;                 // [B,N,256]

    char* ws = (char*)d_ws;
    const size_t MB = 1024u * 1024u;
    float* inp     = (float*)ws;                          // 8 MB
    u16*   WhiT    = (u16*)(ws + 8 * MB);                 // 128 KB
    u16*   WloT    = (u16*)(ws + 8 * MB + 128 * 1024);    // 128 KB
    float* self_s  = (float*)(ws + 8 * MB + 256 * 1024);  // 256 KB
    float* neigh_s = (float*)(ws + 8 * MB + 512 * 1024);  // 256 KB

    wprep<<<16, 256, 0, stream>>>(W, WhiT, WloT);
    gemm_scores<<<NB * NN / 16, 256, 0, stream>>>(
        X, WhiT, WloT, fc1, fc2, inp, self_s, neigh_s);
    gat_agg<<<NB * NN, 256, 0, stream>>>(A, inp, self_s, neigh_s, out);
}